// Round 13
// baseline (31.863 us; speedup 1.0000x reference)
//
#include <hip/hip_runtime.h>
#include <hip/hip_bf16.h>

constexpr int NROWS = 8192;

typedef __attribute__((ext_vector_type(8))) short short8v; // 8 bf16
typedef __attribute__((ext_vector_type(4))) float f32x4;   // MFMA acc

__device__ __forceinline__ unsigned cvt2(float lo, float hi) {
    __hip_bfloat162 h;
    h.x = __float2bfloat16(lo);
    h.y = __float2bfloat16(hi);
    union { __hip_bfloat162 h2; unsigned u; } cv; cv.h2 = h; return cv.u;
}
__device__ __forceinline__ unsigned short f2bfu(float x) {
    __hip_bfloat16 h = __float2bfloat16(x);
    union { __hip_bfloat16 b; unsigned short u; } cv; cv.b = h; return cv.u;
}
// async global->LDS, 16B per lane; LDS dest must be linear (base + lane*16)
__device__ __forceinline__ void gload16(const void* g, void* l) {
    __builtin_amdgcn_global_load_lds(
        (const __attribute__((address_space(1))) unsigned int*)g,
        (__attribute__((address_space(3))) unsigned int*)l,
        16, 0, 0);
}

// ---------------------------------------------------------------------------
// Prep: 4 weight matrices -> bf16, once.  (proven)
// ---------------------------------------------------------------------------
__global__ __launch_bounds__(256) void prep_kernel(
    const float* __restrict__ Wq, const float* __restrict__ Wk,
    const float* __restrict__ Wv, const float* __restrict__ Wp,
    unsigned short* __restrict__ out)
{
    const float* srcs[4] = {Wq, Wk, Wv, Wp};
    const float* s = srcs[blockIdx.y];
    unsigned short* d = out + (size_t)blockIdx.y * 65536;
    int idx = blockIdx.x * 256 + threadIdx.x;
    float4 a = ((const float4*)s)[idx * 2];
    float4 b = ((const float4*)s)[idx * 2 + 1];
    uint4 p;
    p.x = cvt2(a.x, a.y); p.y = cvt2(a.z, a.w);
    p.z = cvt2(b.x, b.y); p.w = cvt2(b.z, b.w);
    ((uint4*)d)[idx] = p;
}

// ---------------------------------------------------------------------------
// Fully-fused kernel v2: 256 blocks x 32 rows x 512 threads (8 waves, 2x4).
// Weight L2 traffic halved vs R12 (128 MB). A staged ONCE per phase (K=512
// in LDS) -> chunk loops have no A-register path (no mid-loop vmcnt drain).
//   1) kv fused GEMM (8 chunks, Wk/Wv dbuf gload_lds)
//   2) k,v(f32+bias) -> BsB overlay; 7 moments/row (16 thr/row)
//   3) q GEMM (A_q restaged; Wq dbuf); x = N/D in-register -> Xs (A overlay)
//   4) proj GEMM (4 ng x 2 c, Wp dbuf) -> out
// LDS 99840 B. Zero intermediate global traffic.
// ---------------------------------------------------------------------------
__global__ __launch_bounds__(512, 1) void fused_kernel(
    const float* __restrict__ xq, const float* __restrict__ xkv,
    const unsigned short* __restrict__ Wbf,
    const float* __restrict__ bq, const float* __restrict__ bk,
    const float* __restrict__ bv, const float* __restrict__ pb,
    float* __restrict__ out)
{
    __shared__ __align__(16) char smem[99840];
    // 0      : Alds [32][520] bf16 (33280)   | overlay later: Xs[32*128] bf16
    // 33280  : BsA[2][128*64] bf16 (32768)
    // 66048  : BsB[2][128*64] bf16 (32768)   | overlay: k_lds,v_lds [32][128] f32
    // 98816  : mom [32][8] f32 (1024)
    unsigned short* Alds = (unsigned short*)smem;
    unsigned short (*BsA)[128 * 64] = (unsigned short (*)[128 * 64])(smem + 33280);
    unsigned short (*BsB)[128 * 64] = (unsigned short (*)[128 * 64])(smem + 66048);
    float* k_lds = (float*)(smem + 66048);
    float* v_lds = (float*)(smem + 66048 + 16384);
    unsigned short* Xs = (unsigned short*)smem;
    float* momp = (float*)(smem + 98816);

    const int m0 = blockIdx.x * 32;
    const int tid = threadIdx.x, lane = tid & 63;
    const int w = tid >> 6, wr = w >> 2, wc = w & 3;   // 2x4 wave grid
    const int brow0 = tid >> 3, bu = tid & 7;          // B stage coords
    const int frow = lane & 15, t16 = lane >> 4;
    const int col_l = frow, row_l = t16 * 4;

    const unsigned short* Wqb = Wbf;
    const unsigned short* Wkb = Wbf + 65536;
    const unsigned short* Wvb = Wbf + 2 * 65536;
    const unsigned short* Wpb = Wbf + 3 * 65536;

    float4 ra[8];

    // ---- load+stage A (32 rows x 512 k, f32->bf16), flat-coalesced --------
#define LDA_ALL(src) { _Pragma("unroll") for (int i = 0; i < 8; ++i) { \
      int idx = tid + i * 512; int row = idx >> 7, c4 = idx & 127; \
      ra[i] = *(const float4*)((src) + (size_t)(m0 + row) * 512 + c4 * 4); } }
#define STA_ALL() { _Pragma("unroll") for (int i = 0; i < 8; ++i) { \
      int idx = tid + i * 512; int row = idx >> 7, c4 = idx & 127; \
      uint2 p; p.x = cvt2(ra[i].x, ra[i].y); p.y = cvt2(ra[i].z, ra[i].w); \
      *(uint2*)(&Alds[row * 520 + c4 * 4]) = p; } }
    // B stage: 128 rows x 64 k bf16 via swizzled gload_lds (2 per thread)
#define STB(Wm, Bsx, c, buf) { _Pragma("unroll") for (int i = 0; i < 2; ++i) { \
      int row = brow0 + i * 64; int su = bu ^ (row & 7); \
      gload16((Wm) + (size_t)row * 512 + (c) * 64 + su * 8, \
              &(Bsx)[buf][(row * 8 + bu) * 8]); } }
#define STBP(ng, c, buf) { _Pragma("unroll") for (int i = 0; i < 2; ++i) { \
      int row = brow0 + i * 64; int su = bu ^ (row & 7); \
      gload16(Wpb + (size_t)((ng) * 128 + row) * 128 + (c) * 64 + su * 8, \
              &BsA[buf][(row * 8 + bu) * 8]); } }

    // ================= 1) kv fused GEMM ====================================
    LDA_ALL(xkv);
    STB(Wkb, BsA, 0, 0); STB(Wvb, BsB, 0, 0);
    STA_ALL();
    __syncthreads();

    f32x4 acck[2] = {}, accv[2] = {};
    for (int c = 0; c < 8; ++c) {
        if (c < 7) { STB(Wkb, BsA, c + 1, (c + 1) & 1); STB(Wvb, BsB, c + 1, (c + 1) & 1); }
        const unsigned short* bk_ = BsA[c & 1];
        const unsigned short* bv_ = BsB[c & 1];
        short8v a[2], bkf[2][2], bvf[2][2];
        #pragma unroll
        for (int kk = 0; kk < 2; ++kk) {
            a[kk] = *(const short8v*)&Alds[(wr * 16 + frow) * 520 + c * 64 + kk * 32 + t16 * 8];
            #pragma unroll
            for (int nf = 0; nf < 2; ++nf) {
                int row = wc * 32 + nf * 16 + frow;
                int u = (kk * 4 + t16) ^ (row & 7);
                bkf[nf][kk] = *(const short8v*)&bk_[row * 64 + u * 8];
                bvf[nf][kk] = *(const short8v*)&bv_[row * 64 + u * 8];
            }
        }
        #pragma unroll
        for (int kk = 0; kk < 2; ++kk)
            #pragma unroll
            for (int nf = 0; nf < 2; ++nf) {
                acck[nf] = __builtin_amdgcn_mfma_f32_16x16x32_bf16(a[kk], bkf[nf][kk], acck[nf], 0, 0, 0);
                accv[nf] = __builtin_amdgcn_mfma_f32_16x16x32_bf16(a[kk], bvf[nf][kk], accv[nf], 0, 0, 0);
            }
        __syncthreads();
    }

    // ================= 2) k,v -> overlay; moments ==========================
    LDA_ALL(xq);   // issue xq HBM loads early; latency hides under epilogue+moments

    // C/D layout: col=lane&15, row=(lane>>4)*4+r  [m89-verified]
    #pragma unroll
    for (int nf = 0; nf < 2; ++nf) {
        int col = wc * 32 + nf * 16 + col_l;
        float bkc = bk[col], bvc = bv[col];
        #pragma unroll
        for (int r4 = 0; r4 < 4; ++r4) {
            int row = wr * 16 + row_l + r4;
            k_lds[row * 128 + col] = acck[nf][r4] + bkc;
            v_lds[row * 128 + col] = accv[nf][r4] + bvc;
        }
    }
    STB(Wqb, BsA, 0, 0);   // BsA free (kv loop done)
    __syncthreads();

    STA_ALL();   // restage A with xq (region free; kv frag reads done)
    {   // moments: 16 threads/row
        const int r = tid >> 4, seg = tid & 15;
        float s[7] = {};
        #pragma unroll
        for (int h = 0; h < 2; ++h) {
            float4 kf = *(const float4*)&k_lds[r * 128 + seg * 8 + h * 4];
            float4 vf = *(const float4*)&v_lds[r * 128 + seg * 8 + h * 4];
            float ke[4] = {kf.x, kf.y, kf.z, kf.w};
            float ve[4] = {vf.x, vf.y, vf.z, vf.w};
            #pragma unroll
            for (int e = 0; e < 4; ++e) {
                float k1 = ke[e], k2 = k1 * k1, k3 = k2 * k1, v1 = ve[e];
                s[0] += k1; s[1] += k2; s[2] += k3;
                s[3] += v1; s[4] += k1 * v1; s[5] += k2 * v1; s[6] += k3 * v1;
            }
        }
        #pragma unroll
        for (int off = 1; off <= 8; off <<= 1)
            #pragma unroll
            for (int t = 0; t < 7; ++t)
                s[t] += __shfl_xor(s[t], off, 64);
        if (seg == 0) {
            #pragma unroll
            for (int t = 0; t < 7; ++t) momp[r * 8 + t] = s[t];
        }
    }
    __syncthreads();

    // ================= 3) q GEMM; x -> Xs ==================================
    f32x4 accq[2] = {};
    for (int c = 0; c < 8; ++c) {
        if (c < 7) STB(Wqb, BsA, c + 1, (c + 1) & 1);
        const unsigned short* bq_ = BsA[c & 1];
        short8v a[2], bf[2][2];
        #pragma unroll
        for (int kk = 0; kk < 2; ++kk) {
            a[kk] = *(const short8v*)&Alds[(wr * 16 + frow) * 520 + c * 64 + kk * 32 + t16 * 8];
            #pragma unroll
            for (int nf = 0; nf < 2; ++nf) {
                int row = wc * 32 + nf * 16 + frow;
                int u = (kk * 4 + t16) ^ (row & 7);
                bf[nf][kk] = *(const short8v*)&bq_[row * 64 + u * 8];
            }
        }
        #pragma unroll
        for (int kk = 0; kk < 2; ++kk)
            #pragma unroll
            for (int nf = 0; nf < 2; ++nf)
                accq[nf] = __builtin_amdgcn_mfma_f32_16x16x32_bf16(a[kk], bf[nf][kk], accq[nf], 0, 0, 0);
        __syncthreads();
    }

    STBP(0, 0, 0);   // proj step-0 staging hides under x evaluation

    {   // x = N(a)/D(a); write bf16 Xs with XOR-8 swizzle (A region overlay)
        float bqc[2];
        #pragma unroll
        for (int nf = 0; nf < 2; ++nf) bqc[nf] = bq[wc * 32 + nf * 16 + col_l];
        #pragma unroll
        for (int r4 = 0; r4 < 4; ++r4) {
            int row = wr * 16 + row_l + r4;
            float sm0 = momp[row * 8 + 0], sm1 = momp[row * 8 + 1];
            float sm2 = momp[row * 8 + 2], sm3 = momp[row * 8 + 3];
            float sm4 = momp[row * 8 + 4], sm5 = momp[row * 8 + 5];
            float sm6 = momp[row * 8 + 6];
            float h2n = 0.5f * sm5, h3n = (1.0f / 6.0f) * sm6;
            float h2d = 0.5f * sm1, h3d = (1.0f / 6.0f) * sm2;
            #pragma unroll
            for (int nf = 0; nf < 2; ++nf) {
                int col = wc * 32 + nf * 16 + col_l;
                float aa = (accq[nf][r4] + bqc[nf]) * (1.0f / 128.0f);
                float xn = sm3 + aa * (sm4 + aa * (h2n + aa * h3n));
                float xd = 128.0f + aa * (sm0 + aa * (h2d + aa * h3d));
                float xv = xn * __builtin_amdgcn_rcpf(xd);
                Xs[row * 128 + (col ^ ((row & 7) << 3))] = f2bfu(xv);
            }
        }
    }
    __syncthreads();

    // ================= 4) proj GEMM ========================================
    f32x4 accp[2] = {};
    for (int s = 0; s < 8; ++s) {
        const int ng = s >> 1, c = s & 1;
        if (s < 7) STBP((s + 1) >> 1, (s + 1) & 1, (s + 1) & 1);
        const unsigned short* bp_ = BsA[s & 1];
        short8v a[2], bf[2][2];
        #pragma unroll
        for (int kk = 0; kk < 2; ++kk) {
            int arow_ = wr * 16 + frow;
            a[kk] = *(const short8v*)&Xs[arow_ * 128
                     + ((c * 64 + kk * 32 + t16 * 8) ^ ((arow_ & 7) << 3))];
            #pragma unroll
            for (int nf = 0; nf < 2; ++nf) {
                int row = wc * 32 + nf * 16 + frow;
                int u = (kk * 4 + t16) ^ (row & 7);
                bf[nf][kk] = *(const short8v*)&bp_[row * 64 + u * 8];
            }
        }
        #pragma unroll
        for (int kk = 0; kk < 2; ++kk)
            #pragma unroll
            for (int nf = 0; nf < 2; ++nf)
                accp[nf] = __builtin_amdgcn_mfma_f32_16x16x32_bf16(a[kk], bf[nf][kk], accp[nf], 0, 0, 0);
        if (c == 1) {
            #pragma unroll
            for (int nf = 0; nf < 2; ++nf) {
                int col = ng * 128 + wc * 32 + nf * 16 + col_l;
                float pbc = pb[col];
                #pragma unroll
                for (int r4 = 0; r4 < 4; ++r4)
                    out[(size_t)(m0 + wr * 16 + row_l + r4) * 512 + col] = accp[nf][r4] + pbc;
                accp[nf] = (f32x4){0.0f, 0.0f, 0.0f, 0.0f};
            }
        }
        __syncthreads();
    }
#undef LDA_ALL
#undef STA_ALL
#undef STB
#undef STBP
}

// ---------------------------------------------------------------------------
extern "C" void kernel_launch(void* const* d_in, const int* in_sizes, int n_in,
                              void* d_out, int out_size, void* d_ws, size_t ws_size,
                              hipStream_t stream) {
    const float* x_q    = (const float*)d_in[0];
    const float* x_kv   = (const float*)d_in[1];
    const float* Wq_w   = (const float*)d_in[2];
    const float* Wq_b   = (const float*)d_in[3];
    const float* Wk_w   = (const float*)d_in[4];
    const float* Wk_b   = (const float*)d_in[5];
    const float* Wv_w   = (const float*)d_in[6];
    const float* Wv_b   = (const float*)d_in[7];
    const float* proj_w = (const float*)d_in[8];
    const float* proj_b = (const float*)d_in[9];
    float* out = (float*)d_out;

    unsigned short* Wbf = (unsigned short*)d_ws;   // 512 KB bf16 weights

    prep_kernel<<<dim3(32, 4), 256, 0, stream>>>(Wq_w, Wk_w, Wv_w, proj_w, Wbf);
    fused_kernel<<<dim3(NROWS / 32), 512, 0, stream>>>(
        x_q, x_kv, Wbf, Wq_b, Wk_b, Wv_b, proj_b, out);
}